// Round 5
// baseline (822.299 us; speedup 1.0000x reference)
//
#include <hip/hip_runtime.h>

#define NODES   65536      // B*N
#define NGRAPH  512        // N
#define BATCH   128        // B
#define HID     128
#define TOUT    12
#define MAXDEG  10
#define NDEG    11
#define EPSV    1e-5f
#define MT      32                 // nodes per conv tile
#define MAXT    (NODES / MT)       // 2048

__device__ __forceinline__ void fma4(float4& a, float s, const float4& w) {
    a.x = fmaf(s, w.x, a.x);
    a.y = fmaf(s, w.y, a.y);
    a.z = fmaf(s, w.z, a.z);
    a.w = fmaf(s, w.w, a.w);
}

// ---------------------------------------------------------------- zero state (every launch: ws is poisoned)
__global__ void k_zero(float4* part4, float* stats1, float* stats2, int* cnt) {
    int i = blockIdx.x * 256 + threadIdx.x;       // grid 512 -> 131072 float4 = 524288 f
    part4[i] = make_float4(0.f, 0.f, 0.f, 0.f);
    if (blockIdx.x == 0) {
        stats1[threadIdx.x] = 0.f;
        stats2[threadIdx.x] = 0.f;
        if (threadIdx.x < 16) cnt[threadIdx.x] = 0;
    }
}

// ---------------------------------------------------------------- bucket nodes by degree
__global__ void k_bucket(const int* __restrict__ deg, int* __restrict__ cnt,
                         int* __restrict__ lists) {
    __shared__ int s_cnt[NDEG];
    __shared__ int s_base[NDEG];
    int t = threadIdx.x;
    if (t < NDEG) s_cnt[t] = 0;
    __syncthreads();
    int i = blockIdx.x * 256 + t;
    int d = deg[i];
    d = d < 0 ? 0 : (d > MAXDEG ? MAXDEG : d);
    int pos = atomicAdd(&s_cnt[d], 1);
    __syncthreads();
    if (t < NDEG) s_base[t] = atomicAdd(&cnt[t], s_cnt[t]);
    __syncthreads();
    lists[d * NODES + s_base[d] + pos] = i;
}

// ---------------------------------------------------------------- build concatenated weights/biases
// Wcat1 [11][160][128]: [0,75)=Wself1, [75,80)=0, [80,155)=Wneigh1[d-1] (0 for d=0), [155,160)=0
__global__ void k_build1(const float* __restrict__ Ws, const float* __restrict__ Wn,
                         float* __restrict__ Wcat) {
    int idx = blockIdx.x * 256 + threadIdx.x;     // < 11*160*32 ; grid 220
    int h4 = idx & 31;
    int k  = (idx >> 5) % 160;
    int d  = idx / (160 * 32);
    float4 v = make_float4(0.f, 0.f, 0.f, 0.f);
    if (k < 75)
        v = *(const float4*)(Ws + ((size_t)d * 75 + k) * 128 + h4 * 4);
    else if (k >= 80 && k < 155 && d >= 1)
        v = *(const float4*)(Wn + ((size_t)(d - 1) * 75 + (k - 80)) * 128 + h4 * 4);
    *(float4*)(Wcat + ((size_t)d * 160 + k) * 128 + h4 * 4) = v;
}
// Wcat2 [11][256][128]: [0,128)=Wself2, [128,256)=Wneigh2[d-1] (0 for d=0)
__global__ void k_build2(const float* __restrict__ Ws, const float* __restrict__ Wn,
                         float* __restrict__ Wcat) {
    int idx = blockIdx.x * 256 + threadIdx.x;     // < 11*256*32 ; grid 352
    int h4 = idx & 31;
    int k  = (idx >> 5) & 255;
    int d  = idx >> 13;
    float4 v = make_float4(0.f, 0.f, 0.f, 0.f);
    if (k < 128)
        v = *(const float4*)(Ws + ((size_t)d * 128 + k) * 128 + h4 * 4);
    else if (d >= 1)
        v = *(const float4*)(Wn + ((size_t)(d - 1) * 128 + (k - 128)) * 128 + h4 * 4);
    *(float4*)(Wcat + ((size_t)d * 256 + k) * 128 + h4 * 4) = v;
}
__global__ void k_bias(const float* bs1, const float* bn1, const float* bs2, const float* bn2,
                       float* bcat1, float* bcat2) {
    int d = blockIdx.x, t = threadIdx.x;          // 11 x 256
    if (t < 128) bcat1[d * 128 + t] = bs1[d * 128 + t] + (d > 0 ? bn1[(d - 1) * 128 + t] : 0.f);
    else { int h = t - 128; bcat2[d * 128 + h] = bs2[d * 128 + h] + (d > 0 ? bn2[(d - 1) * 128 + h] : 0.f); }
}

// ---------------------------------------------------------------- neighbor sums
// layer1: ns1[node][80] (cols 75..79 = 0), x stride 75 (unaligned -> scalar gathers, 4 cols/thread)
__global__ void k_ns1(const float* __restrict__ x, const int* __restrict__ adj,
                      const int* __restrict__ deg, float* __restrict__ ns1) {
    int idx = blockIdx.x * 256 + threadIdx.x;     // < NODES*20 ; grid 5120
    int node = idx / 20;
    int q = idx - node * 20;
    int f = q * 4;
    int d = deg[node];
    d = d < 0 ? 0 : (d > MAXDEG ? MAXDEG : d);
    const int* arow = adj + node * MAXDEG;
    int base = node & ~(NGRAPH - 1);
    float4 s = make_float4(0.f, 0.f, 0.f, 0.f);
    for (int k = 0; k < d; ++k) {
        const float* xr = x + (size_t)(base + arow[k]) * 75 + f;
        if (f + 3 < 75) { s.x += xr[0]; s.y += xr[1]; s.z += xr[2]; s.w += xr[3]; }
        else {
            if (f + 0 < 75) s.x += xr[0];
            if (f + 1 < 75) s.y += xr[1];
            if (f + 2 < 75) s.z += xr[2];
        }
    }
    *(float4*)(ns1 + (size_t)node * 80 + f) = s;
}
// layer2: ns2[node][128], h stride 128 (aligned float4 gathers)
__global__ void k_ns2(const float* __restrict__ h, const int* __restrict__ adj,
                      const int* __restrict__ deg, float* __restrict__ ns2) {
    int idx = blockIdx.x * 256 + threadIdx.x;     // < NODES*32 ; grid 8192
    int node = idx >> 5;
    int f = (idx & 31) * 4;
    int d = deg[node];
    d = d < 0 ? 0 : (d > MAXDEG ? MAXDEG : d);
    const int* arow = adj + node * MAXDEG;
    int base = node & ~(NGRAPH - 1);
    float4 s = make_float4(0.f, 0.f, 0.f, 0.f);
    for (int k = 0; k < d; ++k) {
        float4 v = *(const float4*)(h + (size_t)(base + arow[k]) * HID + f);
        s.x += v.x; s.y += v.y; s.z += v.z; s.w += v.w;
    }
    *(float4*)(ns2 + (size_t)node * HID + f) = s;
}

// ---------------------------------------------------------------- conv: per-degree tiles, chunked dbuf LDS
// S=concat K (160 or 256), KS=self width (75 or 128). Block: 32 nodes x 128 cols,
// 256 thr, each 4 rows x 4 cols. LDS 2 x 32 x 36 floats (9.4 KB) -> 4 blocks/CU.
template<int S, int KS>
__global__ __launch_bounds__(256, 4)
void k_conv(const float* __restrict__ selfF, const float* __restrict__ nsF,
            const float* __restrict__ Wcat, const float* __restrict__ bcat,
            const int* __restrict__ lists, const int* __restrict__ cnt,
            float* __restrict__ out, float* __restrict__ partials) {
    constexpr int NCH = S / 32;
    constexpr int SP  = S / 2;                 // self/ns boundary in concat cols
    constexpr int NSS = (KS == 75) ? 80 : 128; // ns row stride

    __shared__ int   s_ids[MT];
    __shared__ float s_f[2][MT][36];           // +4 pad: conflict-light, 16B-aligned rows

    const int d  = blockIdx.y;
    const int c  = cnt[d];
    const int m0 = blockIdx.x * MT;
    if (m0 >= c) return;
    const int mv = min(MT, c - m0);
    const int t  = threadIdx.x;

    if (t < MT) {
        int j = (t < mv) ? t : 0;              // duplicate a valid id for tail rows
        s_ids[t] = lists[d * NODES + m0 + j];
    }
    __syncthreads();

    const int row = t >> 3;                    // staging: 8 thr/row, 1 float4 each
    const int t8  = t & 7;
    const int id  = s_ids[row];

    auto ld = [&](int cc) -> float4 {
        int f = cc * 32 + t8 * 4;
        if (f < SP) {
            if constexpr (KS == 75) {
                float4 v;
                v.x = (f + 0 < 75) ? selfF[(size_t)id * 75 + f + 0] : 0.f;
                v.y = (f + 1 < 75) ? selfF[(size_t)id * 75 + f + 1] : 0.f;
                v.z = (f + 2 < 75) ? selfF[(size_t)id * 75 + f + 2] : 0.f;
                v.w = (f + 3 < 75) ? selfF[(size_t)id * 75 + f + 3] : 0.f;
                return v;
            } else {
                return *(const float4*)(selfF + (size_t)id * 128 + f);
            }
        }
        return *(const float4*)(nsF + (size_t)id * NSS + (f - SP));
    };

    const int cg = t & 31;
    const int rg = t >> 5;

    float4 bias = *(const float4*)(bcat + d * HID + cg * 4);
    float4 acc0 = bias, acc1 = bias, acc2 = bias, acc3 = bias;
    const float* Wb = Wcat + (size_t)d * S * HID + cg * 4;

    *(float4*)(&s_f[0][row][t8 * 4]) = ld(0);
    __syncthreads();

    for (int cc = 0; cc < NCH; ++cc) {
        const int buf = cc & 1;
        const bool more = (cc + 1 < NCH);
        float4 nxt;
        if (more) nxt = ld(cc + 1);            // issue loads early; write after compute

        const float* Wc  = Wb + cc * 32 * HID;
        const float* fr0 = &s_f[buf][rg * 4 + 0][0];
        const float* fr1 = &s_f[buf][rg * 4 + 1][0];
        const float* fr2 = &s_f[buf][rg * 4 + 2][0];
        const float* fr3 = &s_f[buf][rg * 4 + 3][0];
        #pragma unroll
        for (int k4 = 0; k4 < 8; ++k4) {
            float4 f0 = *(const float4*)(fr0 + k4 * 4);
            float4 f1 = *(const float4*)(fr1 + k4 * 4);
            float4 f2 = *(const float4*)(fr2 + k4 * 4);
            float4 f3 = *(const float4*)(fr3 + k4 * 4);
            const float* wp = Wc + k4 * 4 * HID;
            float4 w0 = *(const float4*)(wp);
            float4 w1 = *(const float4*)(wp + HID);
            float4 w2 = *(const float4*)(wp + 2 * HID);
            float4 w3 = *(const float4*)(wp + 3 * HID);
            fma4(acc0, f0.x, w0); fma4(acc0, f0.y, w1); fma4(acc0, f0.z, w2); fma4(acc0, f0.w, w3);
            fma4(acc1, f1.x, w0); fma4(acc1, f1.y, w1); fma4(acc1, f1.z, w2); fma4(acc1, f1.w, w3);
            fma4(acc2, f2.x, w0); fma4(acc2, f2.y, w1); fma4(acc2, f2.z, w2); fma4(acc2, f2.w, w3);
            fma4(acc3, f3.x, w0); fma4(acc3, f3.y, w1); fma4(acc3, f3.z, w2); fma4(acc3, f3.w, w3);
        }
        if (more) *(float4*)(&s_f[buf ^ 1][row][t8 * 4]) = nxt;
        __syncthreads();
    }

    // epilogue: store + BN partial sums
    float4 cs = make_float4(0.f, 0.f, 0.f, 0.f), cq = make_float4(0.f, 0.f, 0.f, 0.f);
#define EPI(J, A) { int i = rg * 4 + J; if (i < mv) { \
        *(float4*)(out + (size_t)s_ids[i] * HID + cg * 4) = A; \
        cs.x += A.x; cs.y += A.y; cs.z += A.z; cs.w += A.w; \
        cq.x += A.x * A.x; cq.y += A.y * A.y; cq.z += A.z * A.z; cq.w += A.w * A.w; } }
    EPI(0, acc0) EPI(1, acc1) EPI(2, acc2) EPI(3, acc3)
#undef EPI
    __syncthreads();
    float* red = &s_f[0][0][0];                // 2304 floats >= 2048
    *(float4*)(&red[rg * 256 + cg * 4]) = cs;
    *(float4*)(&red[rg * 256 + 128 + cg * 4]) = cq;
    __syncthreads();
    float tot = 0.f;
    #pragma unroll
    for (int g = 0; g < 8; ++g) tot += red[g * 256 + t];
    atomicAdd(&partials[(size_t)blockIdx.x * 256 + t], tot);
}

// ---------------------------------------------------------------- drain BN partials (and re-zero them)
__global__ void k_redstats(float* __restrict__ partials, float* __restrict__ stats) {
    int t = threadIdx.x;
    float acc = 0.f;
    for (int bx = blockIdx.x; bx < MAXT; bx += gridDim.x) {
        float* p = partials + (size_t)bx * 256 + t;
        acc += *p;
        *p = 0.f;
    }
    atomicAdd(&stats[t], acc);
}

// ---------------------------------------------------------------- BN + ReLU in place
__global__ void k_bnrelu(float* __restrict__ h, const float* __restrict__ stats,
                         const float* __restrict__ gamma, const float* __restrict__ beta) {
    int idx = blockIdx.x * 256 + threadIdx.x;    // < NODES*HID/4
    int h0 = (idx * 4) & (HID - 1);
    float4 v = *(float4*)(h + (size_t)idx * 4);
    const float inv = 1.f / (float)NODES;
    float* vp = (float*)&v;
    #pragma unroll
    for (int j = 0; j < 4; ++j) {
        int col = h0 + j;
        float mu  = stats[col] * inv;
        float var = stats[HID + col] * inv - mu * mu;
        float rs  = rsqrtf(var + EPSV);
        float sc  = gamma[col] * rs;
        float sh  = beta[col] - mu * sc;
        vp[j] = fmaxf(fmaf(vp[j], sc, sh), 0.f);
    }
    *(float4*)(h + (size_t)idx * 4) = v;
}

// ---------------------------------------------------------------- BN2 + ReLU + mean over N + dense
__global__ void k_pool_dense(const float* __restrict__ h2, const float* __restrict__ stats,
                             const float* __restrict__ gamma, const float* __restrict__ beta,
                             const float* __restrict__ Wd, const float* __restrict__ bd,
                             float* __restrict__ outp) {
    __shared__ float s_part[4][HID];
    __shared__ float s_pool[HID];
    const int b = blockIdx.x;
    const int t = threadIdx.x;        // 512
    const int hcol = t & (HID - 1);
    const int q = t >> 7;             // 0..3
    const float inv = 1.f / (float)NODES;
    float mu  = stats[hcol] * inv;
    float var = stats[HID + hcol] * inv - mu * mu;
    float rs  = rsqrtf(var + EPSV);
    float sc  = gamma[hcol] * rs;
    float sh  = beta[hcol] - mu * sc;
    float acc = 0.f;
    const float* hp = h2 + ((size_t)b * NGRAPH + q * 128) * HID + hcol;
    #pragma unroll 4
    for (int n = 0; n < 128; ++n)
        acc += fmaxf(fmaf(hp[(size_t)n * HID], sc, sh), 0.f);
    s_part[q][hcol] = acc;
    __syncthreads();
    if (t < HID)
        s_pool[t] = (s_part[0][t] + s_part[1][t] + s_part[2][t] + s_part[3][t]) * (1.f / NGRAPH);
    __syncthreads();
    if (t < TOUT) {
        float o = bd[t];
        for (int hh = 0; hh < HID; ++hh)
            o = fmaf(s_pool[hh], Wd[hh * TOUT + t], o);
        outp[b * TOUT + t] = o;
    }
}

// ---------------------------------------------------------------- launch
extern "C" void kernel_launch(void* const* d_in, const int* in_sizes, int n_in,
                              void* d_out, int out_size, void* d_ws, size_t ws_size,
                              hipStream_t stream) {
    const float* x   = (const float*)d_in[0];
    const int*   adj = (const int*)d_in[1];
    const int*   deg = (const int*)d_in[2];
    const float* Wn1 = (const float*)d_in[3];
    const float* Ws1 = (const float*)d_in[4];
    const float* bn1 = (const float*)d_in[5];
    const float* bs1 = (const float*)d_in[6];
    const float* g1  = (const float*)d_in[7];
    const float* be1 = (const float*)d_in[8];
    const float* Wn2 = (const float*)d_in[9];
    const float* Ws2 = (const float*)d_in[10];
    const float* bn2 = (const float*)d_in[11];
    const float* bs2 = (const float*)d_in[12];
    const float* g2  = (const float*)d_in[13];
    const float* be2 = (const float*)d_in[14];
    const float* Wd  = (const float*)d_in[15];
    const float* bd  = (const float*)d_in[16];

    float* ws     = (float*)d_ws;
    float* h1     = ws;                          // 8388608
    float* ns1    = ws + 8388608;                // 5242880 (aliased: h2 reuses this region)
    float* h2     = ws + 8388608;                // 8388608 (written after ns1 is dead)
    float* ns2    = ws + 16777216;               // 8388608
    float* part   = ws + 25165824;               // 524288
    float* Wcat1  = ws + 25690112;               // 225280
    float* Wcat2  = ws + 25915392;               // 360448
    float* bcat1  = ws + 26275840;               // 1408
    float* bcat2  = ws + 26277248;               // 1408
    float* stats1 = ws + 26278656;               // 256
    float* stats2 = ws + 26278912;               // 256
    int*   cnt    = (int*)(ws + 26279168);       // 16
    int*   lists  = cnt + 16;                    // 720896 ints  -> total ~108 MB

    k_zero<<<512, 256, 0, stream>>>((float4*)part, stats1, stats2, cnt);
    k_bucket<<<NODES / 256, 256, 0, stream>>>(deg, cnt, lists);
    k_build1<<<220, 256, 0, stream>>>(Ws1, Wn1, Wcat1);
    k_build2<<<352, 256, 0, stream>>>(Ws2, Wn2, Wcat2);
    k_bias<<<NDEG, 256, 0, stream>>>(bs1, bn1, bs2, bn2, bcat1, bcat2);

    // ----- layer 1
    k_ns1<<<NODES * 20 / 256, 256, 0, stream>>>(x, adj, deg, ns1);
    k_conv<160, 75><<<dim3(MAXT, NDEG), 256, 0, stream>>>(x, ns1, Wcat1, bcat1,
                                                          lists, cnt, h1, part);
    k_redstats<<<32, 256, 0, stream>>>(part, stats1);
    k_bnrelu<<<NODES * HID / 4 / 256, 256, 0, stream>>>(h1, stats1, g1, be1);

    // ----- layer 2
    k_ns2<<<NODES * 32 / 256, 256, 0, stream>>>(h1, adj, deg, ns2);
    k_conv<256, 128><<<dim3(MAXT, NDEG), 256, 0, stream>>>(h1, ns2, Wcat2, bcat2,
                                                           lists, cnt, h2, part);
    k_redstats<<<32, 256, 0, stream>>>(part, stats2);

    // ----- BN2 + ReLU + pool + dense
    k_pool_dense<<<BATCH, 512, 0, stream>>>(h2, stats2, g2, be2, Wd, bd, (float*)d_out);
}

// Round 7
// 375.372 us; speedup vs baseline: 2.1906x; 2.1906x over previous
//
#include <hip/hip_runtime.h>

#define NODES   65536      // B*N
#define NGRAPH  512        // N
#define BATCH   128        // B
#define HID     128
#define TOUT    12
#define MAXDEG  10
#define NDEG    11
#define EPSV    1e-5f
#define MT      128                // nodes per conv tile
#define MAXT    (NODES / MT)       // 512

typedef float f32x4 __attribute__((ext_vector_type(4)));

__device__ __forceinline__ f32x4 ntload(const float* p) {
    return __builtin_nontemporal_load((const f32x4*)p);
}
__device__ __forceinline__ void ntstore(float* p, f32x4 v) {
    __builtin_nontemporal_store(v, (f32x4*)p);
}

// ---------------------------------------------------------------- zero state
__global__ void k_zero(f32x4* part4, float* stats1, float* stats2, int* cnt) {
    int i = blockIdx.x * 256 + threadIdx.x;       // grid 128 -> 32768 f32x4 = 131072 f
    part4[i] = 0.f;
    if (blockIdx.x == 0) {
        stats1[threadIdx.x] = 0.f;
        stats2[threadIdx.x] = 0.f;
        if (threadIdx.x < 16) cnt[threadIdx.x] = 0;
    }
}

// ---------------------------------------------------------------- bucket nodes by degree
__global__ void k_bucket(const int* __restrict__ deg, int* __restrict__ cnt,
                         int* __restrict__ lists) {
    __shared__ int s_cnt[NDEG];
    __shared__ int s_base[NDEG];
    int t = threadIdx.x;
    if (t < NDEG) s_cnt[t] = 0;
    __syncthreads();
    int i = blockIdx.x * 256 + t;
    int d = deg[i];
    d = d < 0 ? 0 : (d > MAXDEG ? MAXDEG : d);
    int pos = atomicAdd(&s_cnt[d], 1);
    __syncthreads();
    if (t < NDEG) s_base[t] = atomicAdd(&cnt[t], s_cnt[t]);
    __syncthreads();
    lists[d * NODES + s_base[d] + pos] = i;
}

// ---------------------------------------------------------------- build concatenated weights/biases
// Wcat1 [11][160][128]: [0,75)=Wself1, [75,80)=0, [80,155)=Wneigh1[d-1] (0 for d=0), [155,160)=0
__global__ void k_build1(const float* __restrict__ Ws, const float* __restrict__ Wn,
                         float* __restrict__ Wcat) {
    int idx = blockIdx.x * 256 + threadIdx.x;     // < 11*160*32 ; grid 220
    int h4 = idx & 31;
    int k  = (idx >> 5) % 160;
    int d  = idx / (160 * 32);
    f32x4 v = 0.f;
    if (k < 75)
        v = *(const f32x4*)(Ws + ((size_t)d * 75 + k) * 128 + h4 * 4);
    else if (k >= 80 && k < 155 && d >= 1)
        v = *(const f32x4*)(Wn + ((size_t)(d - 1) * 75 + (k - 80)) * 128 + h4 * 4);
    *(f32x4*)(Wcat + ((size_t)d * 160 + k) * 128 + h4 * 4) = v;
}
// Wcat2 [11][256][128]: [0,128)=Wself2, [128,256)=Wneigh2[d-1] (0 for d=0)
__global__ void k_build2(const float* __restrict__ Ws, const float* __restrict__ Wn,
                         float* __restrict__ Wcat) {
    int idx = blockIdx.x * 256 + threadIdx.x;     // < 11*256*32 ; grid 352
    int h4 = idx & 31;
    int k  = (idx >> 5) & 255;
    int d  = idx >> 13;
    f32x4 v = 0.f;
    if (k < 128)
        v = *(const f32x4*)(Ws + ((size_t)d * 128 + k) * 128 + h4 * 4);
    else if (d >= 1)
        v = *(const f32x4*)(Wn + ((size_t)(d - 1) * 128 + (k - 128)) * 128 + h4 * 4);
    *(f32x4*)(Wcat + ((size_t)d * 256 + k) * 128 + h4 * 4) = v;
}
__global__ void k_bias(const float* bs1, const float* bn1, const float* bs2, const float* bn2,
                       float* bcat1, float* bcat2) {
    int d = blockIdx.x, t = threadIdx.x;          // 11 x 256
    if (t < 128) bcat1[d * 128 + t] = bs1[d * 128 + t] + (d > 0 ? bn1[(d - 1) * 128 + t] : 0.f);
    else { int h = t - 128; bcat2[d * 128 + h] = bs2[d * 128 + h] + (d > 0 ? bn2[(d - 1) * 128 + h] : 0.f); }
}

// ---------------------------------------------------------------- layer-1 pack: feats1[node][160] = [x(75)|0(5)|ns1(80)]
__global__ void k_ns1(const float* __restrict__ x, const int* __restrict__ adj,
                      const int* __restrict__ deg, float* __restrict__ feats1) {
    int idx = blockIdx.x * 256 + threadIdx.x;     // < NODES*20 ; grid 5120
    int node = idx / 20;
    int q = idx - node * 20;
    int f = q * 4;
    int d = deg[node];
    d = d < 0 ? 0 : (d > MAXDEG ? MAXDEG : d);
    const int* arow = adj + node * MAXDEG;
    int base = node & ~(NGRAPH - 1);
    f32x4 s = 0.f;
    for (int k = 0; k < d; ++k) {
        const float* xr = x + (size_t)(base + arow[k]) * 75 + f;
        if (f + 3 < 75) { s.x += xr[0]; s.y += xr[1]; s.z += xr[2]; s.w += xr[3]; }
        else {
            if (f + 0 < 75) s.x += xr[0];
            if (f + 1 < 75) s.y += xr[1];
            if (f + 2 < 75) s.z += xr[2];
        }
    }
    *(f32x4*)(feats1 + (size_t)node * 160 + 80 + f) = s;
    // x copy (zero-padded)
    f32x4 v = 0.f;
    const float* xs = x + (size_t)node * 75 + f;
    if (f + 3 < 75) { v.x = xs[0]; v.y = xs[1]; v.z = xs[2]; v.w = xs[3]; }
    else {
        if (f + 0 < 75) v.x = xs[0];
        if (f + 1 < 75) v.y = xs[1];
        if (f + 2 < 75) v.z = xs[2];
    }
    *(f32x4*)(feats1 + (size_t)node * 160 + f) = v;
}

// ---------------------------------------------------------------- layer-2 gather: feats2[node][128..256) = ns2
// source = bn-relu'd h1 living in feats2[.][0..128)
__global__ void k_ns2(const float* __restrict__ feats2r, const int* __restrict__ adj,
                      const int* __restrict__ deg, float* __restrict__ feats2w) {
    int idx = blockIdx.x * 256 + threadIdx.x;     // < NODES*32 ; grid 8192
    int node = idx >> 5;
    int f = (idx & 31) * 4;
    int d = deg[node];
    d = d < 0 ? 0 : (d > MAXDEG ? MAXDEG : d);
    const int* arow = adj + node * MAXDEG;
    int base = node & ~(NGRAPH - 1);
    f32x4 s = 0.f;
    for (int k = 0; k < d; ++k) {
        f32x4 v = *(const f32x4*)(feats2r + (size_t)(base + arow[k]) * 256 + f);
        s += v;
    }
    *(f32x4*)(feats2w + (size_t)node * 256 + 128 + f) = s;
}

// ---------------------------------------------------------------- conv: grouped GEMM, W+F^T chunk tiles in LDS
// Block: 128 nodes x 128 cols, 256 thr, each 8 rows x 8 cols. K chunked by 32,
// double-buffered. LDS 66 KB -> 2 blocks/CU. Features/out non-temporal; W cached.
template<int S, int OS>
__global__ __launch_bounds__(256, 4)
void k_conv(const float* __restrict__ feats, const float* __restrict__ Wcat,
            const float* __restrict__ bcat, const int* __restrict__ lists,
            const int* __restrict__ cnt, float* __restrict__ out,
            float* __restrict__ partials) {
    constexpr int NCH = S / 32;

    __shared__ int   s_ids[MT];
    __shared__ float sW[2][32][128];
    __shared__ float sF[2][32][128];   // transposed: sF[k][row]

    const int d  = blockIdx.y;
    const int c  = cnt[d];
    const int m0 = blockIdx.x * MT;
    if (m0 >= c) return;
    const int mv = min(MT, c - m0);
    const int t  = threadIdx.x;

    if (t < MT) s_ids[t] = lists[d * NODES + m0 + (t < mv ? t : 0)];
    __syncthreads();

    // staging roles
    const int kw = t >> 3;             // W row 0..31 (8 thr/row)
    const int cw = (t & 7) * 16;       // W col base
    const int rf = t >> 1;             // F row 0..127 (2 thr/row)
    const int ks = (t & 1) * 16;       // F k base
    const float* Wbase = Wcat + (size_t)d * S * 128;
    const float* Fbase = feats + (size_t)s_ids[rf] * S;

    f32x4 w0, w1, w2, w3, f0, f1, f2, f3;
    auto LOAD = [&](int ch) {
        const float* wp = Wbase + (size_t)(ch * 32 + kw) * 128 + cw;
        w0 = *(const f32x4*)(wp);      w1 = *(const f32x4*)(wp + 4);
        w2 = *(const f32x4*)(wp + 8);  w3 = *(const f32x4*)(wp + 12);
        const float* fp = Fbase + ch * 32 + ks;
        f0 = ntload(fp); f1 = ntload(fp + 4); f2 = ntload(fp + 8); f3 = ntload(fp + 12);
    };
    auto STORE = [&](int buf) {
        *(f32x4*)&sW[buf][kw][cw + 0]  = w0;
        *(f32x4*)&sW[buf][kw][cw + 4]  = w1;
        *(f32x4*)&sW[buf][kw][cw + 8]  = w2;
        *(f32x4*)&sW[buf][kw][cw + 12] = w3;
        sF[buf][ks +  0][rf] = f0.x; sF[buf][ks +  1][rf] = f0.y;
        sF[buf][ks +  2][rf] = f0.z; sF[buf][ks +  3][rf] = f0.w;
        sF[buf][ks +  4][rf] = f1.x; sF[buf][ks +  5][rf] = f1.y;
        sF[buf][ks +  6][rf] = f1.z; sF[buf][ks +  7][rf] = f1.w;
        sF[buf][ks +  8][rf] = f2.x; sF[buf][ks +  9][rf] = f2.y;
        sF[buf][ks + 10][rf] = f2.z; sF[buf][ks + 11][rf] = f2.w;
        sF[buf][ks + 12][rf] = f3.x; sF[buf][ks + 13][rf] = f3.y;
        sF[buf][ks + 14][rf] = f3.z; sF[buf][ks + 15][rf] = f3.w;
    };

    const int cg = t & 15;             // col group: cols cg*8..+7
    const int rg = t >> 4;             // row group: rows rg*8..+7

    f32x4 acc[8][2];
    {
        f32x4 b0 = *(const f32x4*)(bcat + d * HID + cg * 8);
        f32x4 b1 = *(const f32x4*)(bcat + d * HID + cg * 8 + 4);
        #pragma unroll
        for (int j = 0; j < 8; ++j) { acc[j][0] = b0; acc[j][1] = b1; }
    }

    LOAD(0); STORE(0);
    __syncthreads();

    for (int ch = 0; ch < NCH; ++ch) {
        const int buf = ch & 1;
        const bool more = (ch + 1 < NCH);
        if (more) LOAD(ch + 1);        // issue early; LDS-write after compute
        #pragma unroll 8
        for (int k = 0; k < 32; ++k) {
            f32x4 wA = *(const f32x4*)&sW[buf][k][cg * 8];
            f32x4 wB = *(const f32x4*)&sW[buf][k][cg * 8 + 4];
            f32x4 fA = *(const f32x4*)&sF[buf][k][rg * 8];
            f32x4 fB = *(const f32x4*)&sF[buf][k][rg * 8 + 4];
            acc[0][0] += fA.x * wA;  acc[0][1] += fA.x * wB;
            acc[1][0] += fA.y * wA;  acc[1][1] += fA.y * wB;
            acc[2][0] += fA.z * wA;  acc[2][1] += fA.z * wB;
            acc[3][0] += fA.w * wA;  acc[3][1] += fA.w * wB;
            acc[4][0] += fB.x * wA;  acc[4][1] += fB.x * wB;
            acc[5][0] += fB.y * wA;  acc[5][1] += fB.y * wB;
            acc[6][0] += fB.z * wA;  acc[6][1] += fB.z * wB;
            acc[7][0] += fB.w * wA;  acc[7][1] += fB.w * wB;
        }
        if (more) STORE(buf ^ 1);      // safe: all waves past barrier of prev iter
        __syncthreads();
    }

    // epilogue: NT store rows + BN partial sums (valid rows only)
    f32x4 cs0 = 0.f, cs1 = 0.f, cq0 = 0.f, cq1 = 0.f;
    #pragma unroll
    for (int j = 0; j < 8; ++j) {
        int i = rg * 8 + j;
        if (i < mv) {
            float* op = out + (size_t)s_ids[i] * OS + cg * 8;
            ntstore(op, acc[j][0]);
            ntstore(op + 4, acc[j][1]);
            cs0 += acc[j][0]; cs1 += acc[j][1];
            cq0 += acc[j][0] * acc[j][0]; cq1 += acc[j][1] * acc[j][1];
        }
    }
    __syncthreads();
    float* red = &sW[0][0][0];         // 16 rg x 256 floats = 16 KB
    *(f32x4*)&red[rg * 256 + cg * 8]       = cs0;
    *(f32x4*)&red[rg * 256 + cg * 8 + 4]   = cs1;
    *(f32x4*)&red[rg * 256 + 128 + cg * 8]     = cq0;
    *(f32x4*)&red[rg * 256 + 128 + cg * 8 + 4] = cq1;
    __syncthreads();
    float tot = 0.f;
    #pragma unroll
    for (int g = 0; g < 16; ++g) tot += red[g * 256 + t];
    atomicAdd(&partials[(size_t)blockIdx.x * 256 + t], tot);
}

// ---------------------------------------------------------------- drain BN partials (and re-zero)
__global__ void k_redstats(float* __restrict__ partials, float* __restrict__ stats) {
    int t = threadIdx.x;
    float acc = 0.f;
    for (int bx = blockIdx.x; bx < MAXT; bx += gridDim.x) {
        float* p = partials + (size_t)bx * 256 + t;
        acc += *p;
        *p = 0.f;
    }
    atomicAdd(&stats[t], acc);
}

// ---------------------------------------------------------------- BN + ReLU in place on feats2 cols [0,128)
__global__ void k_bnrelu(float* __restrict__ feats2, const float* __restrict__ stats,
                         const float* __restrict__ gamma, const float* __restrict__ beta) {
    int idx = blockIdx.x * 256 + threadIdx.x;    // < NODES*32 ; grid 8192
    int node = idx >> 5;
    int c4 = (idx & 31) * 4;
    float* p = feats2 + (size_t)node * 256 + c4;
    f32x4 v = *(f32x4*)p;
    const float inv = 1.f / (float)NODES;
    #pragma unroll
    for (int j = 0; j < 4; ++j) {
        int col = c4 + j;
        float mu  = stats[col] * inv;
        float var = stats[HID + col] * inv - mu * mu;
        float rs  = rsqrtf(var + EPSV);
        float sc  = gamma[col] * rs;
        float sh  = beta[col] - mu * sc;
        v[j] = fmaxf(fmaf(v[j], sc, sh), 0.f);
    }
    *(f32x4*)p = v;
}

// ---------------------------------------------------------------- BN2 + ReLU + mean over N + dense
__global__ void k_pool_dense(const float* __restrict__ h2, const float* __restrict__ stats,
                             const float* __restrict__ gamma, const float* __restrict__ beta,
                             const float* __restrict__ Wd, const float* __restrict__ bd,
                             float* __restrict__ outp) {
    __shared__ float s_part[4][HID];
    __shared__ float s_pool[HID];
    const int b = blockIdx.x;
    const int t = threadIdx.x;        // 512
    const int hcol = t & (HID - 1);
    const int q = t >> 7;             // 0..3
    const float inv = 1.f / (float)NODES;
    float mu  = stats[hcol] * inv;
    float var = stats[HID + hcol] * inv - mu * mu;
    float rs  = rsqrtf(var + EPSV);
    float sc  = gamma[hcol] * rs;
    float sh  = beta[hcol] - mu * sc;
    float acc = 0.f;
    const float* hp = h2 + ((size_t)b * NGRAPH + q * 128) * HID + hcol;
    #pragma unroll 4
    for (int n = 0; n < 128; ++n)
        acc += fmaxf(fmaf(hp[(size_t)n * HID], sc, sh), 0.f);
    s_part[q][hcol] = acc;
    __syncthreads();
    if (t < HID)
        s_pool[t] = (s_part[0][t] + s_part[1][t] + s_part[2][t] + s_part[3][t]) * (1.f / NGRAPH);
    __syncthreads();
    if (t < TOUT) {
        float o = bd[t];
        for (int hh = 0; hh < HID; ++hh)
            o = fmaf(s_pool[hh], Wd[hh * TOUT + t], o);
        outp[b * TOUT + t] = o;
    }
}

// ---------------------------------------------------------------- launch
extern "C" void kernel_launch(void* const* d_in, const int* in_sizes, int n_in,
                              void* d_out, int out_size, void* d_ws, size_t ws_size,
                              hipStream_t stream) {
    const float* x   = (const float*)d_in[0];
    const int*   adj = (const int*)d_in[1];
    const int*   deg = (const int*)d_in[2];
    const float* Wn1 = (const float*)d_in[3];
    const float* Ws1 = (const float*)d_in[4];
    const float* bn1 = (const float*)d_in[5];
    const float* bs1 = (const float*)d_in[6];
    const float* g1  = (const float*)d_in[7];
    const float* be1 = (const float*)d_in[8];
    const float* Wn2 = (const float*)d_in[9];
    const float* Ws2 = (const float*)d_in[10];
    const float* bn2 = (const float*)d_in[11];
    const float* bs2 = (const float*)d_in[12];
    const float* g2  = (const float*)d_in[13];
    const float* be2 = (const float*)d_in[14];
    const float* Wd  = (const float*)d_in[15];
    const float* bd  = (const float*)d_in[16];

    float* ws     = (float*)d_ws;
    float* feats1 = ws;                          // 10,485,760 f  [x|pad|ns1], stride 160
    float* h2     = ws;                          // alias: feats1 dead when conv2 writes
    float* feats2 = ws + 10485760;               // 16,777,216 f  [h1bn|ns2], stride 256
    float* Wcat1  = ws + 27262976;               // 225,280
    float* Wcat2  = ws + 27488256;               // 360,448
    float* bcat1  = ws + 27848704;               // 1,408
    float* bcat2  = ws + 27850112;               // 1,408
    float* part   = ws + 27851520;               // 131,072 (MAXT*256)
    float* stats1 = ws + 27982592;               // 256
    float* stats2 = ws + 27982848;               // 256
    int*   cnt    = (int*)(ws + 27983104);       // 16
    int*   lists  = cnt + 16;                    // 720,896 ints -> total ~115 MB

    k_zero<<<128, 256, 0, stream>>>((f32x4*)part, stats1, stats2, cnt);
    k_bucket<<<NODES / 256, 256, 0, stream>>>(deg, cnt, lists);
    k_build1<<<220, 256, 0, stream>>>(Ws1, Wn1, Wcat1);
    k_build2<<<352, 256, 0, stream>>>(Ws2, Wn2, Wcat2);
    k_bias<<<NDEG, 256, 0, stream>>>(bs1, bn1, bs2, bn2, bcat1, bcat2);

    // ----- layer 1: pack feats1, conv -> feats2 cols [0,128)
    k_ns1<<<NODES * 20 / 256, 256, 0, stream>>>(x, adj, deg, feats1);
    k_conv<160, 256><<<dim3(MAXT, NDEG), 256, 0, stream>>>(feats1, Wcat1, bcat1,
                                                           lists, cnt, feats2, part);
    k_redstats<<<32, 256, 0, stream>>>(part, stats1);
    k_bnrelu<<<8192, 256, 0, stream>>>(feats2, stats1, g1, be1);

    // ----- layer 2: gather ns2 into feats2 cols [128,256), conv -> h2
    k_ns2<<<8192, 256, 0, stream>>>(feats2, adj, deg, feats2);
    k_conv<256, 128><<<dim3(MAXT, NDEG), 256, 0, stream>>>(feats2, Wcat2, bcat2,
                                                           lists, cnt, h2, part);
    k_redstats<<<32, 256, 0, stream>>>(part, stats2);

    // ----- BN2 + ReLU + pool + dense
    k_pool_dense<<<BATCH, 512, 0, stream>>>(h2, stats2, g2, be2, Wd, bd, (float*)d_out);
}

// Round 9
// 356.963 us; speedup vs baseline: 2.3036x; 1.0516x over previous
//
#include <hip/hip_runtime.h>

#define NODES   65536      // B*N
#define NGRAPH  512        // N
#define BATCH   128        // B
#define HID     128
#define TOUT    12
#define MAXDEG  10
#define NDEG    11
#define EPSV    1e-5f
#define MT      128                // nodes per conv tile
#define NTILES  (NODES / MT + NDEG)   // 523: exact upper bound on worker tiles
#define PCAP    544                   // partials rows capacity

typedef float f32x4 __attribute__((ext_vector_type(4)));

__device__ __forceinline__ f32x4 ntload(const float* p) {
    return __builtin_nontemporal_load((const f32x4*)p);
}
__device__ __forceinline__ void ntstore(float* p, f32x4 v) {
    __builtin_nontemporal_store(v, (f32x4*)p);
}

// ---------------------------------------------------------------- zero state
__global__ void k_zero(f32x4* part4, float* stats1, float* stats2, int* cnt) {
    int i = blockIdx.x * 256 + threadIdx.x;       // grid 136 -> 34816 f32x4 = PCAP*256 f
    part4[i] = 0.f;
    if (blockIdx.x == 0) {
        stats1[threadIdx.x] = 0.f;
        stats2[threadIdx.x] = 0.f;
        if (threadIdx.x < 16) cnt[threadIdx.x] = 0;
    }
}

// ---------------------------------------------------------------- bucket nodes by degree
__global__ void k_bucket(const int* __restrict__ deg, int* __restrict__ cnt,
                         int* __restrict__ lists) {
    __shared__ int s_cnt[NDEG];
    __shared__ int s_base[NDEG];
    int t = threadIdx.x;
    if (t < NDEG) s_cnt[t] = 0;
    __syncthreads();
    int i = blockIdx.x * 256 + t;
    int d = deg[i];
    d = d < 0 ? 0 : (d > MAXDEG ? MAXDEG : d);
    int pos = atomicAdd(&s_cnt[d], 1);
    __syncthreads();
    if (t < NDEG) s_base[t] = atomicAdd(&cnt[t], s_cnt[t]);
    __syncthreads();
    lists[d * NODES + s_base[d] + pos] = i;
}

// ---------------------------------------------------------------- tile table: offs[d] = first tile of degree d
__global__ void k_plan(const int* __restrict__ cnt, int* __restrict__ offs) {
    if (threadIdx.x == 0) {
        int acc = 0;
        offs[0] = 0;
        for (int d = 0; d < NDEG; ++d) {
            acc += (cnt[d] + MT - 1) / MT;
            offs[d + 1] = acc;
        }
    }
}

// ---------------------------------------------------------------- build concatenated weights/biases
// Wcat1 [11][160][128]: [0,75)=Wself1, [75,80)=0, [80,155)=Wneigh1[d-1] (0 for d=0), [155,160)=0
__global__ void k_build1(const float* __restrict__ Ws, const float* __restrict__ Wn,
                         float* __restrict__ Wcat) {
    int idx = blockIdx.x * 256 + threadIdx.x;     // < 11*160*32 ; grid 220
    int h4 = idx & 31;
    int k  = (idx >> 5) % 160;
    int d  = idx / (160 * 32);
    f32x4 v = 0.f;
    if (k < 75)
        v = *(const f32x4*)(Ws + ((size_t)d * 75 + k) * 128 + h4 * 4);
    else if (k >= 80 && k < 155 && d >= 1)
        v = *(const f32x4*)(Wn + ((size_t)(d - 1) * 75 + (k - 80)) * 128 + h4 * 4);
    *(f32x4*)(Wcat + ((size_t)d * 160 + k) * 128 + h4 * 4) = v;
}
// Wcat2 [11][256][128]: [0,128)=Wself2, [128,256)=Wneigh2[d-1] (0 for d=0)
__global__ void k_build2(const float* __restrict__ Ws, const float* __restrict__ Wn,
                         float* __restrict__ Wcat) {
    int idx = blockIdx.x * 256 + threadIdx.x;     // < 11*256*32 ; grid 352
    int h4 = idx & 31;
    int k  = (idx >> 5) & 255;
    int d  = idx >> 13;
    f32x4 v = 0.f;
    if (k < 128)
        v = *(const f32x4*)(Ws + ((size_t)d * 128 + k) * 128 + h4 * 4);
    else if (d >= 1)
        v = *(const f32x4*)(Wn + ((size_t)(d - 1) * 128 + (k - 128)) * 128 + h4 * 4);
    *(f32x4*)(Wcat + ((size_t)d * 256 + k) * 128 + h4 * 4) = v;
}
__global__ void k_bias(const float* bs1, const float* bn1, const float* bs2, const float* bn2,
                       float* bcat1, float* bcat2) {
    int d = blockIdx.x, t = threadIdx.x;          // 11 x 256
    if (t < 128) bcat1[d * 128 + t] = bs1[d * 128 + t] + (d > 0 ? bn1[(d - 1) * 128 + t] : 0.f);
    else { int h = t - 128; bcat2[d * 128 + h] = bs2[d * 128 + h] + (d > 0 ? bn2[(d - 1) * 128 + h] : 0.f); }
}

// ---------------------------------------------------------------- layer-1 pack: feats1[node][160] = [x(75)|0(5)|ns1(80)]
__global__ void k_ns1(const float* __restrict__ x, const int* __restrict__ adj,
                      const int* __restrict__ deg, float* __restrict__ feats1) {
    int idx = blockIdx.x * 256 + threadIdx.x;     // < NODES*20 ; grid 5120
    int node = idx / 20;
    int q = idx - node * 20;
    int f = q * 4;
    int d = deg[node];
    d = d < 0 ? 0 : (d > MAXDEG ? MAXDEG : d);
    const int* arow = adj + node * MAXDEG;
    int base = node & ~(NGRAPH - 1);
    f32x4 s = 0.f;
    for (int k = 0; k < d; ++k) {
        const float* xr = x + (size_t)(base + arow[k]) * 75 + f;
        if (f + 3 < 75) { s.x += xr[0]; s.y += xr[1]; s.z += xr[2]; s.w += xr[3]; }
        else {
            if (f + 0 < 75) s.x += xr[0];
            if (f + 1 < 75) s.y += xr[1];
            if (f + 2 < 75) s.z += xr[2];
        }
    }
    *(f32x4*)(feats1 + (size_t)node * 160 + 80 + f) = s;
    // x copy (zero-padded)
    f32x4 v = 0.f;
    const float* xs = x + (size_t)node * 75 + f;
    if (f + 3 < 75) { v.x = xs[0]; v.y = xs[1]; v.z = xs[2]; v.w = xs[3]; }
    else {
        if (f + 0 < 75) v.x = xs[0];
        if (f + 1 < 75) v.y = xs[1];
        if (f + 2 < 75) v.z = xs[2];
    }
    *(f32x4*)(feats1 + (size_t)node * 160 + f) = v;
}

// ---------------------------------------------------------------- layer-2 gather: feats2[node][128..256) = ns2
// source = bn-relu'd h1 living in feats2[.][0..128)
__global__ void k_ns2(const float* __restrict__ feats2r, const int* __restrict__ adj,
                      const int* __restrict__ deg, float* __restrict__ feats2w) {
    int idx = blockIdx.x * 256 + threadIdx.x;     // < NODES*32 ; grid 8192
    int node = idx >> 5;
    int f = (idx & 31) * 4;
    int d = deg[node];
    d = d < 0 ? 0 : (d > MAXDEG ? MAXDEG : d);
    const int* arow = adj + node * MAXDEG;
    int base = node & ~(NGRAPH - 1);
    f32x4 s = 0.f;
    for (int k = 0; k < d; ++k) {
        f32x4 v = *(const f32x4*)(feats2r + (size_t)(base + arow[k]) * 256 + f);
        s += v;
    }
    *(f32x4*)(feats2w + (size_t)node * 256 + 128 + f) = s;
}

// ---------------------------------------------------------------- conv: grouped GEMM, exact 1D tile grid
// Block: 128 nodes x 128 cols, 512 thr (8 waves), each 8 rows x 4 cols.
// K chunked by 32, double-buffered W+F^T in LDS (66 KB -> 2 blocks/CU = 16 waves/CU).
template<int S, int OS>
__global__ __launch_bounds__(512, 4)
void k_conv(const float* __restrict__ feats, const float* __restrict__ Wcat,
            const float* __restrict__ bcat, const int* __restrict__ lists,
            const int* __restrict__ cnt, const int* __restrict__ offs,
            float* __restrict__ out, float* __restrict__ partials) {
    constexpr int NCH = S / 32;

    __shared__ int   s_ids[MT];
    __shared__ float sW[2][32][128];
    __shared__ float sF[2][32][132];   // transposed: sF[k][row], pad 132 for alignment

    const int bid = blockIdx.x;
    if (bid >= offs[NDEG]) return;
    int d = 0;
    #pragma unroll
    for (int q = 1; q < NDEG; ++q) d += (bid >= offs[q]);
    const int c  = cnt[d];
    const int m0 = (bid - offs[d]) * MT;
    const int mv = min(MT, c - m0);
    const int t  = threadIdx.x;

    if (t < MT) s_ids[t] = lists[d * NODES + m0 + (t < mv ? t : 0)];
    __syncthreads();

    // staging roles
    const int kw = t >> 5;             // W rows kw, kw+16 (1 f32x4 each)
    const int c4 = t & 31;             // W col quad
    const int fr = t >> 3;             // F rows fr, fr+64
    const int kq = t & 7;              // F k quad
    const float* Wbase = Wcat + (size_t)d * S * 128;
    const float* Fb0 = feats + (size_t)s_ids[fr] * S;
    const float* Fb1 = feats + (size_t)s_ids[fr + 64] * S;

    f32x4 w0, w1, f0, f1;
    auto LOAD = [&](int ch) {
        const float* wp = Wbase + (size_t)(ch * 32 + kw) * 128 + c4 * 4;
        w0 = *(const f32x4*)(wp);
        w1 = *(const f32x4*)(wp + 16 * 128);
        const float* fp0 = Fb0 + ch * 32 + kq * 4;
        const float* fp1 = Fb1 + ch * 32 + kq * 4;
        f0 = ntload(fp0);
        f1 = ntload(fp1);
    };
    auto STORE = [&](int buf) {
        *(f32x4*)&sW[buf][kw][c4 * 4]      = w0;
        *(f32x4*)&sW[buf][kw + 16][c4 * 4] = w1;
        sF[buf][kq * 4 + 0][fr] = f0.x; sF[buf][kq * 4 + 1][fr] = f0.y;
        sF[buf][kq * 4 + 2][fr] = f0.z; sF[buf][kq * 4 + 3][fr] = f0.w;
        sF[buf][kq * 4 + 0][fr + 64] = f1.x; sF[buf][kq * 4 + 1][fr + 64] = f1.y;
        sF[buf][kq * 4 + 2][fr + 64] = f1.z; sF[buf][kq * 4 + 3][fr + 64] = f1.w;
    };

    const int cg = t & 31;             // col group: cols cg*4..+3
    const int rg = t >> 5;             // row group: rows rg*8..+7

    f32x4 acc[8];
    {
        f32x4 b = *(const f32x4*)(bcat + d * HID + cg * 4);
        #pragma unroll
        for (int j = 0; j < 8; ++j) acc[j] = b;
    }

    LOAD(0); STORE(0);
    __syncthreads();

    for (int ch = 0; ch < NCH; ++ch) {
        const int buf = ch & 1;
        const bool more = (ch + 1 < NCH);
        if (more) LOAD(ch + 1);        // issue early; LDS-write after compute
        #pragma unroll 8
        for (int k = 0; k < 32; ++k) {
            f32x4 wv = *(const f32x4*)&sW[buf][k][cg * 4];
            f32x4 fA = *(const f32x4*)&sF[buf][k][rg * 8];
            f32x4 fB = *(const f32x4*)&sF[buf][k][rg * 8 + 4];
            acc[0] += fA.x * wv;
            acc[1] += fA.y * wv;
            acc[2] += fA.z * wv;
            acc[3] += fA.w * wv;
            acc[4] += fB.x * wv;
            acc[5] += fB.y * wv;
            acc[6] += fB.z * wv;
            acc[7] += fB.w * wv;
        }
        if (more) STORE(buf ^ 1);      // safe: all waves past barrier of prev iter
        __syncthreads();
    }

    // epilogue: NT store rows + BN partial sums (valid rows only)
    f32x4 cs = 0.f, cq = 0.f;
    #pragma unroll
    for (int j = 0; j < 8; ++j) {
        int i = rg * 8 + j;
        if (i < mv) {
            ntstore(out + (size_t)s_ids[i] * OS + cg * 4, acc[j]);
            cs += acc[j];
            cq += acc[j] * acc[j];
        }
    }
    __syncthreads();
    float* red = &sW[0][0][0];         // 16 rg x 256 floats = 16 KB
    *(f32x4*)&red[rg * 256 + cg * 4]       = cs;
    *(f32x4*)&red[rg * 256 + 128 + cg * 4] = cq;
    __syncthreads();
    if (t < 256) {
        float tot = 0.f;
        #pragma unroll
        for (int g = 0; g < 16; ++g) tot += red[g * 256 + t];
        partials[(size_t)bid * 256 + t] = tot;   // bid unique: plain store
    }
}

// ---------------------------------------------------------------- drain BN partials (and re-zero)
__global__ void k_redstats(float* __restrict__ partials, float* __restrict__ stats) {
    int t = threadIdx.x;
    float acc = 0.f;
    for (int bx = blockIdx.x; bx < PCAP; bx += gridDim.x) {
        float* p = partials + (size_t)bx * 256 + t;
        acc += *p;
        *p = 0.f;
    }
    atomicAdd(&stats[t], acc);
}

// ---------------------------------------------------------------- BN + ReLU in place on feats2 cols [0,128)
__global__ void k_bnrelu(float* __restrict__ feats2, const float* __restrict__ stats,
                         const float* __restrict__ gamma, const float* __restrict__ beta) {
    int idx = blockIdx.x * 256 + threadIdx.x;    // < NODES*32 ; grid 8192
    int node = idx >> 5;
    int c4 = (idx & 31) * 4;
    float* p = feats2 + (size_t)node * 256 + c4;
    f32x4 v = *(f32x4*)p;
    const float inv = 1.f / (float)NODES;
    #pragma unroll
    for (int j = 0; j < 4; ++j) {
        int col = c4 + j;
        float mu  = stats[col] * inv;
        float var = stats[HID + col] * inv - mu * mu;
        float rs  = rsqrtf(var + EPSV);
        float sc  = gamma[col] * rs;
        float sh  = beta[col] - mu * sc;
        v[j] = fmaxf(fmaf(v[j], sc, sh), 0.f);
    }
    *(f32x4*)p = v;
}

// ---------------------------------------------------------------- BN2 + ReLU + mean over N + dense
__global__ void k_pool_dense(const float* __restrict__ h2, const float* __restrict__ stats,
                             const float* __restrict__ gamma, const float* __restrict__ beta,
                             const float* __restrict__ Wd, const float* __restrict__ bd,
                             float* __restrict__ outp) {
    __shared__ float s_part[4][HID];
    __shared__ float s_pool[HID];
    const int b = blockIdx.x;
    const int t = threadIdx.x;        // 512
    const int hcol = t & (HID - 1);
    const int q = t >> 7;             // 0..3
    const float inv = 1.f / (float)NODES;
    float mu  = stats[hcol] * inv;
    float var = stats[HID + hcol] * inv - mu * mu;
    float rs  = rsqrtf(var + EPSV);
    float sc  = gamma[hcol] * rs;
    float sh  = beta[hcol] - mu * sc;
    float acc = 0.f;
    const float* hp = h2 + ((size_t)b * NGRAPH + q * 128) * HID + hcol;
    #pragma unroll 4
    for (int n = 0; n < 128; ++n)
        acc += fmaxf(fmaf(hp[(size_t)n * HID], sc, sh), 0.f);
    s_part[q][hcol] = acc;
    __syncthreads();
    if (t < HID)
        s_pool[t] = (s_part[0][t] + s_part[1][t] + s_part[2][t] + s_part[3][t]) * (1.f / NGRAPH);
    __syncthreads();
    if (t < TOUT) {
        float o = bd[t];
        for (int hh = 0; hh < HID; ++hh)
            o = fmaf(s_pool[hh], Wd[hh * TOUT + t], o);
        outp[b * TOUT + t] = o;
    }
}

// ---------------------------------------------------------------- launch
extern "C" void kernel_launch(void* const* d_in, const int* in_sizes, int n_in,
                              void* d_out, int out_size, void* d_ws, size_t ws_size,
                              hipStream_t stream) {
    const float* x   = (const float*)d_in[0];
    const int*   adj = (const int*)d_in[1];
    const int*   deg = (const int*)d_in[2];
    const float* Wn1 = (const float*)d_in[3];
    const float* Ws1 = (const float*)d_in[4];
    const float* bn1 = (const float*)d_in[5];
    const float* bs1 = (const float*)d_in[6];
    const float* g1  = (const float*)d_in[7];
    const float* be1 = (const float*)d_in[8];
    const float* Wn2 = (const float*)d_in[9];
    const float* Ws2 = (const float*)d_in[10];
    const float* bn2 = (const float*)d_in[11];
    const float* bs2 = (const float*)d_in[12];
    const float* g2  = (const float*)d_in[13];
    const float* be2 = (const float*)d_in[14];
    const float* Wd  = (const float*)d_in[15];
    const float* bd  = (const float*)d_in[16];

    float* ws     = (float*)d_ws;
    float* feats1 = ws;                          // 10,485,760 f  [x|pad|ns1], stride 160
    float* h2     = ws;                          // alias: feats1 dead when conv2 writes
    float* feats2 = ws + 10485760;               // 16,777,216 f  [h1bn|ns2], stride 256
    float* Wcat1  = ws + 27262976;               // 225,280
    float* Wcat2  = ws + 27488256;               // 360,448
    float* bcat1  = ws + 27848704;               // 1,408
    float* bcat2  = ws + 27850112;               // 1,408
    float* part   = ws + 27851520;               // 139,264 (PCAP*256)
    float* stats1 = ws + 27990784;               // 256
    float* stats2 = ws + 27991040;               // 256
    int*   cnt    = (int*)(ws + 27991296);       // 16
    int*   offs   = cnt + 16;                    // 16
    int*   lists  = cnt + 32;                    // 720,896 ints -> total ~115 MB

    k_zero<<<PCAP / 4, 256, 0, stream>>>((f32x4*)part, stats1, stats2, cnt);
    k_bucket<<<NODES / 256, 256, 0, stream>>>(deg, cnt, lists);
    k_plan<<<1, 64, 0, stream>>>(cnt, offs);
    k_build1<<<220, 256, 0, stream>>>(Ws1, Wn1, Wcat1);
    k_build2<<<352, 256, 0, stream>>>(Ws2, Wn2, Wcat2);
    k_bias<<<NDEG, 256, 0, stream>>>(bs1, bn1, bs2, bn2, bcat1, bcat2);

    // ----- layer 1: pack feats1, conv -> feats2 cols [0,128)
    k_ns1<<<NODES * 20 / 256, 256, 0, stream>>>(x, adj, deg, feats1);
    k_conv<160, 256><<<NTILES, 512, 0, stream>>>(feats1, Wcat1, bcat1,
                                                 lists, cnt, offs, feats2, part);
    k_redstats<<<32, 256, 0, stream>>>(part, stats1);
    k_bnrelu<<<8192, 256, 0, stream>>>(feats2, stats1, g1, be1);

    // ----- layer 2: gather ns2 into feats2 cols [128,256), conv -> h2
    k_ns2<<<8192, 256, 0, stream>>>(feats2, adj, deg, feats2);
    k_conv<256, 128><<<NTILES, 512, 0, stream>>>(feats2, Wcat2, bcat2,
                                                 lists, cnt, offs, h2, part);
    k_redstats<<<32, 256, 0, stream>>>(part, stats2);

    // ----- BN2 + ReLU + pool + dense
    k_pool_dense<<<BATCH, 512, 0, stream>>>(h2, stats2, g2, be2, Wd, bd, (float*)d_out);
}

// Round 11
// 352.006 us; speedup vs baseline: 2.3360x; 1.0141x over previous
//
#include <hip/hip_runtime.h>

#define NODES   65536      // B*N
#define NGRAPH  512        // N
#define BATCH   128        // B
#define HID     128
#define TOUT    12
#define MAXDEG  10
#define NDEG    11
#define EPSV    1e-5f
#define MT      64                 // nodes per conv tile
#define NTILES  (NODES / MT + NDEG)   // 1035: exact upper bound on worker tiles
#define PCAP    1056                  // partials rows capacity (mult of 4)

typedef float f32x4 __attribute__((ext_vector_type(4)));

__device__ __forceinline__ f32x4 ntload(const float* p) {
    return __builtin_nontemporal_load((const f32x4*)p);
}
__device__ __forceinline__ void ntstore(float* p, f32x4 v) {
    __builtin_nontemporal_store(v, (f32x4*)p);
}

// ---------------------------------------------------------------- zero state
__global__ void k_zero(f32x4* part4, float* stats1, float* stats2, int* cnt) {
    int i = blockIdx.x * 256 + threadIdx.x;       // grid PCAP/4 -> PCAP*256 floats
    part4[i] = 0.f;
    if (blockIdx.x == 0) {
        stats1[threadIdx.x] = 0.f;
        stats2[threadIdx.x] = 0.f;
        if (threadIdx.x < 16) cnt[threadIdx.x] = 0;
    }
}

// ---------------------------------------------------------------- bucket nodes by degree
__global__ void k_bucket(const int* __restrict__ deg, int* __restrict__ cnt,
                         int* __restrict__ lists) {
    __shared__ int s_cnt[NDEG];
    __shared__ int s_base[NDEG];
    int t = threadIdx.x;
    if (t < NDEG) s_cnt[t] = 0;
    __syncthreads();
    int i = blockIdx.x * 256 + t;
    int d = deg[i];
    d = d < 0 ? 0 : (d > MAXDEG ? MAXDEG : d);
    int pos = atomicAdd(&s_cnt[d], 1);
    __syncthreads();
    if (t < NDEG) s_base[t] = atomicAdd(&cnt[t], s_cnt[t]);
    __syncthreads();
    lists[d * NODES + s_base[d] + pos] = i;
}

// ---------------------------------------------------------------- tile table: offs[d] = first tile of degree d
__global__ void k_plan(const int* __restrict__ cnt, int* __restrict__ offs) {
    if (threadIdx.x == 0) {
        int acc = 0;
        offs[0] = 0;
        for (int d = 0; d < NDEG; ++d) {
            acc += (cnt[d] + MT - 1) / MT;
            offs[d + 1] = acc;
        }
    }
}

// ---------------------------------------------------------------- build concatenated weights/biases
// Wcat1 [11][160][128]: [0,75)=Wself1, [75,80)=0, [80,155)=Wneigh1[d-1] (0 for d=0), [155,160)=0
__global__ void k_build1(const float* __restrict__ Ws, const float* __restrict__ Wn,
                         float* __restrict__ Wcat) {
    int idx = blockIdx.x * 256 + threadIdx.x;     // < 11*160*32 ; grid 220
    int h4 = idx & 31;
    int k  = (idx >> 5) % 160;
    int d  = idx / (160 * 32);
    f32x4 v = 0.f;
    if (k < 75)
        v = *(const f32x4*)(Ws + ((size_t)d * 75 + k) * 128 + h4 * 4);
    else if (k >= 80 && k < 155 && d >= 1)
        v = *(const f32x4*)(Wn + ((size_t)(d - 1) * 75 + (k - 80)) * 128 + h4 * 4);
    *(f32x4*)(Wcat + ((size_t)d * 160 + k) * 128 + h4 * 4) = v;
}
// Wcat2 [11][256][128]: [0,128)=Wself2, [128,256)=Wneigh2[d-1] (0 for d=0)
__global__ void k_build2(const float* __restrict__ Ws, const float* __restrict__ Wn,
                         float* __restrict__ Wcat) {
    int idx = blockIdx.x * 256 + threadIdx.x;     // < 11*256*32 ; grid 352
    int h4 = idx & 31;
    int k  = (idx >> 5) & 255;
    int d  = idx >> 13;
    f32x4 v = 0.f;
    if (k < 128)
        v = *(const f32x4*)(Ws + ((size_t)d * 128 + k) * 128 + h4 * 4);
    else if (d >= 1)
        v = *(const f32x4*)(Wn + ((size_t)(d - 1) * 128 + (k - 128)) * 128 + h4 * 4);
    *(f32x4*)(Wcat + ((size_t)d * 256 + k) * 128 + h4 * 4) = v;
}
__global__ void k_bias(const float* bs1, const float* bn1, const float* bs2, const float* bn2,
                       float* bcat1, float* bcat2) {
    int d = blockIdx.x, t = threadIdx.x;          // 11 x 256
    if (t < 128) bcat1[d * 128 + t] = bs1[d * 128 + t] + (d > 0 ? bn1[(d - 1) * 128 + t] : 0.f);
    else { int h = t - 128; bcat2[d * 128 + h] = bs2[d * 128 + h] + (d > 0 ? bn2[(d - 1) * 128 + h] : 0.f); }
}

// ---------------------------------------------------------------- layer-1 pack: feats1[node][160] = [x(75)|0(5)|ns1(80)]
__global__ void k_ns1(const float* __restrict__ x, const int* __restrict__ adj,
                      const int* __restrict__ deg, float* __restrict__ feats1) {
    int idx = blockIdx.x * 256 + threadIdx.x;     // < NODES*20 ; grid 5120
    int node = idx / 20;
    int q = idx - node * 20;
    int f = q * 4;
    int d = deg[node];
    d = d < 0 ? 0 : (d > MAXDEG ? MAXDEG : d);
    const int* arow = adj + node * MAXDEG;
    int base = node & ~(NGRAPH - 1);
    f32x4 s = 0.f;
    for (int k = 0; k < d; ++k) {
        const float* xr = x + (size_t)(base + arow[k]) * 75 + f;
        if (f + 3 < 75) { s.x += xr[0]; s.y += xr[1]; s.z += xr[2]; s.w += xr[3]; }
        else {
            if (f + 0 < 75) s.x += xr[0];
            if (f + 1 < 75) s.y += xr[1];
            if (f + 2 < 75) s.z += xr[2];
        }
    }
    *(f32x4*)(feats1 + (size_t)node * 160 + 80 + f) = s;
    // x copy (zero-padded)
    f32x4 v = 0.f;
    const float* xs = x + (size_t)node * 75 + f;
    if (f + 3 < 75) { v.x = xs[0]; v.y = xs[1]; v.z = xs[2]; v.w = xs[3]; }
    else {
        if (f + 0 < 75) v.x = xs[0];
        if (f + 1 < 75) v.y = xs[1];
        if (f + 2 < 75) v.z = xs[2];
    }
    *(f32x4*)(feats1 + (size_t)node * 160 + f) = v;
}

// ---------------------------------------------------------------- layer-2 gather: feats2[node][128..256) = ns2
// source = bn-relu'd h1 living in feats2[.][0..128)
__global__ void k_ns2(const float* __restrict__ feats2r, const int* __restrict__ adj,
                      const int* __restrict__ deg, float* __restrict__ feats2w) {
    int idx = blockIdx.x * 256 + threadIdx.x;     // < NODES*32 ; grid 8192
    int node = idx >> 5;
    int f = (idx & 31) * 4;
    int d = deg[node];
    d = d < 0 ? 0 : (d > MAXDEG ? MAXDEG : d);
    const int* arow = adj + node * MAXDEG;
    int base = node & ~(NGRAPH - 1);
    f32x4 s = 0.f;
    for (int k = 0; k < d; ++k) {
        f32x4 v = *(const f32x4*)(feats2r + (size_t)(base + arow[k]) * 256 + f);
        s += v;
    }
    *(f32x4*)(feats2w + (size_t)node * 256 + 128 + f) = s;
}

// ---------------------------------------------------------------- conv: grouped GEMM, exact 1D tile grid
// Block: 64 nodes x 128 cols, 256 thr (4 waves), each 8 rows x 4 cols.
// K chunked by 16, reg-prefetch dbuf W+F^T in LDS (~25 KB -> 6 blocks/CU = 24 waves/CU).
template<int S, int OS>
__global__ __launch_bounds__(256, 6)
void k_conv(const float* __restrict__ feats, const float* __restrict__ Wcat,
            const float* __restrict__ bcat, const int* __restrict__ lists,
            const int* __restrict__ cnt, const int* __restrict__ offs,
            float* __restrict__ out, float* __restrict__ partials) {
    constexpr int NCH = S / 16;

    __shared__ int   s_ids[MT];
    __shared__ float sW[2][16][128];
    __shared__ float sF[2][16][68];    // transposed: sF[k][row]; stride 68 -> 2-way stores (free)

    const int bid = blockIdx.x;
    if (bid >= offs[NDEG]) return;
    int d = 0;
    #pragma unroll
    for (int q = 1; q < NDEG; ++q) d += (bid >= offs[q]);
    const int c  = cnt[d];
    const int m0 = (bid - offs[d]) * MT;
    const int mv = min(MT, c - m0);
    const int t  = threadIdx.x;

    if (t < MT) s_ids[t] = lists[d * NODES + m0 + (t < mv ? t : 0)];
    __syncthreads();

    // staging roles
    const int kw = t >> 5;             // W rows kw, kw+8 (1 f32x4 each)
    const int c4 = t & 31;             // W col quad
    const int frow = t >> 2;           // F row 0..63
    const int kq = t & 3;              // F k quad within chunk
    const float* Wbase = Wcat + (size_t)d * S * 128;
    const float* Frow = feats + (size_t)s_ids[frow] * S;

    f32x4 w0, w1, f0;
    auto LOAD = [&](int ch) {
        const float* wp = Wbase + (size_t)(ch * 16 + kw) * 128 + c4 * 4;
        w0 = *(const f32x4*)(wp);
        w1 = *(const f32x4*)(wp + 8 * 128);
        f0 = ntload(Frow + ch * 16 + kq * 4);
    };
    auto STORE = [&](int buf) {
        *(f32x4*)&sW[buf][kw][c4 * 4]     = w0;
        *(f32x4*)&sW[buf][kw + 8][c4 * 4] = w1;
        sF[buf][kq * 4 + 0][frow] = f0.x;
        sF[buf][kq * 4 + 1][frow] = f0.y;
        sF[buf][kq * 4 + 2][frow] = f0.z;
        sF[buf][kq * 4 + 3][frow] = f0.w;
    };

    const int cg = t & 31;             // col group: cols cg*4..+3
    const int rg = t >> 5;             // row group: rows rg*8..+7

    f32x4 acc[8];
    {
        f32x4 b = *(const f32x4*)(bcat + d * HID + cg * 4);
        #pragma unroll
        for (int j = 0; j < 8; ++j) acc[j] = b;
    }

    LOAD(0); STORE(0);
    __syncthreads();

    for (int ch = 0; ch < NCH; ++ch) {
        const int buf = ch & 1;
        const bool more = (ch + 1 < NCH);
        if (more) LOAD(ch + 1);        // issue early; LDS-write after compute
        #pragma unroll 8
        for (int k = 0; k < 16; ++k) {
            f32x4 wv = *(const f32x4*)&sW[buf][k][cg * 4];
            f32x4 fA = *(const f32x4*)&sF[buf][k][rg * 8];
            f32x4 fB = *(const f32x4*)&sF[buf][k][rg * 8 + 4];
            acc[0] += fA.x * wv;
            acc[1] += fA.y * wv;
            acc[2] += fA.z * wv;
            acc[3] += fA.w * wv;
            acc[4] += fB.x * wv;
            acc[5] += fB.y * wv;
            acc[6] += fB.z * wv;
            acc[7] += fB.w * wv;
        }
        if (more) STORE(buf ^ 1);      // safe: all waves past barrier of prev iter
        __syncthreads();
    }

    // epilogue: NT store rows + BN partial sums (valid rows only)
    f32x4 cs = 0.f, cq = 0.f;
    #pragma unroll
    for (int j = 0; j < 8; ++j) {
        int i = rg * 8 + j;
        if (i < mv) {
            ntstore(out + (size_t)s_ids[i] * OS + cg * 4, acc[j]);
            cs += acc[j];
            cq += acc[j] * acc[j];
        }
    }
    __syncthreads();
    float* red = &sW[0][0][0];         // 8 rg x 256 floats = 2048 <= 4096 avail
    *(f32x4*)&red[rg * 256 + cg * 4]       = cs;
    *(f32x4*)&red[rg * 256 + 128 + cg * 4] = cq;
    __syncthreads();
    {
        float tot = 0.f;
        #pragma unroll
        for (int g = 0; g < 8; ++g) tot += red[g * 256 + t];
        partials[(size_t)bid * 256 + t] = tot;   // bid unique: plain store
    }
}

// ---------------------------------------------------------------- drain BN partials (and re-zero)
__global__ void k_redstats(float* __restrict__ partials, float* __restrict__ stats) {
    int t = threadIdx.x;
    float acc = 0.f;
    for (int bx = blockIdx.x; bx < PCAP; bx += gridDim.x) {
        float* p = partials + (size_t)bx * 256 + t;
        acc += *p;
        *p = 0.f;
    }
    atomicAdd(&stats[t], acc);
}

// ---------------------------------------------------------------- BN + ReLU in place on feats2 cols [0,128)
__global__ void k_bnrelu(float* __restrict__ feats2, const float* __restrict__ stats,
                         const float* __restrict__ gamma, const float* __restrict__ beta) {
    int idx = blockIdx.x * 256 + threadIdx.x;    // < NODES*32 ; grid 8192
    int node = idx >> 5;
    int c4 = (idx & 31) * 4;
    float* p = feats2 + (size_t)node * 256 + c4;
    f32x4 v = *(f32x4*)p;
    const float inv = 1.f / (float)NODES;
    #pragma unroll
    for (int j = 0; j < 4; ++j) {
        int col = c4 + j;
        float mu  = stats[col] * inv;
        float var = stats[HID + col] * inv - mu * mu;
        float rs  = rsqrtf(var + EPSV);
        float sc  = gamma[col] * rs;
        float sh  = beta[col] - mu * sc;
        v[j] = fmaxf(fmaf(v[j], sc, sh), 0.f);
    }
    *(f32x4*)p = v;
}

// ---------------------------------------------------------------- BN2 + ReLU + mean over N + dense
__global__ void k_pool_dense(const float* __restrict__ h2, const float* __restrict__ stats,
                             const float* __restrict__ gamma, const float* __restrict__ beta,
                             const float* __restrict__ Wd, const float* __restrict__ bd,
                             float* __restrict__ outp) {
    __shared__ float s_part[4][HID];
    __shared__ float s_pool[HID];
    const int b = blockIdx.x;
    const int t = threadIdx.x;        // 512
    const int hcol = t & (HID - 1);
    const int q = t >> 7;             // 0..3
    const float inv = 1.f / (float)NODES;
    float mu  = stats[hcol] * inv;
    float var = stats[HID + hcol] * inv - mu * mu;
    float rs  = rsqrtf(var + EPSV);
    float sc  = gamma[hcol] * rs;
    float sh  = beta[hcol] - mu * sc;
    float acc = 0.f;
    const float* hp = h2 + ((size_t)b * NGRAPH + q * 128) * HID + hcol;
    #pragma unroll 4
    for (int n = 0; n < 128; ++n)
        acc += fmaxf(fmaf(hp[(size_t)n * HID], sc, sh), 0.f);
    s_part[q][hcol] = acc;
    __syncthreads();
    if (t < HID)
        s_pool[t] = (s_part[0][t] + s_part[1][t] + s_part[2][t] + s_part[3][t]) * (1.f / NGRAPH);
    __syncthreads();
    if (t < TOUT) {
        float o = bd[t];
        for (int hh = 0; hh < HID; ++hh)
            o = fmaf(s_pool[hh], Wd[hh * TOUT + t], o);
        outp[b * TOUT + t] = o;
    }
}

// ---------------------------------------------------------------- launch
extern "C" void kernel_launch(void* const* d_in, const int* in_sizes, int n_in,
                              void* d_out, int out_size, void* d_ws, size_t ws_size,
                              hipStream_t stream) {
    const float* x   = (const float*)d_in[0];
    const int*   adj = (const int*)d_in[1];
    const int*   deg = (const int*)d_in[2];
    const float* Wn1 = (const float*)d_in[3];
    const float* Ws1 = (const float*)d_in[4];
    const float* bn1 = (const float*)d_in[5];
    const float* bs1 = (const float*)d_in[6];
    const float* g1  = (const float*)d_in[7];
    const float* be1 = (const float*)d_in[8];
    const float* Wn2 = (const float*)d_in[9];
    const float* Ws2 = (const float*)d_in[10];
    const float* bn2 = (const float*)d_in[11];
    const float* bs2 = (const float*)d_in[12];
    const float* g2  = (const float*)d_in[13];
    const float* be2 = (const float*)d_in[14];
    const float* Wd  = (const float*)d_in[15];
    const float* bd  = (const float*)d_in[16];

    float* ws     = (float*)d_ws;
    float* feats1 = ws;                          // 10,485,760 f  [x|pad|ns1], stride 160
    float* h2     = ws;                          // alias: feats1 dead when conv2 writes
    float* feats2 = ws + 10485760;               // 16,777,216 f  [h1bn|ns2], stride 256
    float* Wcat1  = ws + 27262976;               // 225,280
    float* Wcat2  = ws + 27488256;               // 360,448
    float* bcat1  = ws + 27848704;               // 1,408
    float* bcat2  = ws + 27850112;               // 1,408
    float* part   = ws + 27851520;               // 270,336 (PCAP*256)
    float* stats1 = ws + 28121856;               // 256
    float* stats2 = ws + 28122112;               // 256
    int*   cnt    = (int*)(ws + 28122368);       // 16
    int*   offs   = cnt + 16;                    // 16
    int*   lists  = cnt + 32;                    // 720,896 ints -> total ~115.5 MB

    k_zero<<<PCAP / 4, 256, 0, stream>>>((f32x4*)part, stats1, stats2, cnt);
    k_bucket<<<NODES / 256, 256, 0, stream>>>(deg, cnt, lists);
    k_plan<<<1, 64, 0, stream>>>(cnt, offs);
    k_build1<<<220, 256, 0, stream>>>(Ws1, Wn1, Wcat1);
    k_build2<<<352, 256, 0, stream>>>(Ws2, Wn2, Wcat2);
    k_bias<<<NDEG, 256, 0, stream>>>(bs1, bn1, bs2, bn2, bcat1, bcat2);

    // ----- layer 1: pack feats1, conv -> feats2 cols [0,128)
    k_ns1<<<NODES * 20 / 256, 256, 0, stream>>>(x, adj, deg, feats1);
    k_conv<160, 256><<<NTILES, 256, 0, stream>>>(feats1, Wcat1, bcat1,
                                                 lists, cnt, offs, feats2, part);
    k_redstats<<<32, 256, 0, stream>>>(part, stats1);
    k_bnrelu<<<8192, 256, 0, stream>>>(feats2, stats1, g1, be1);

    // ----- layer 2: gather ns2 into feats2 cols [128,256), conv -> h2
    k_ns2<<<8192, 256, 0, stream>>>(feats2, adj, deg, feats2);
    k_conv<256, 128><<<NTILES, 256, 0, stream>>>(feats2, Wcat2, bcat2,
                                                 lists, cnt, offs, h2, part);
    k_redstats<<<32, 256, 0, stream>>>(part, stats2);

    // ----- BN2 + ReLU + pool + dense
    k_pool_dense<<<BATCH, 512, 0, stream>>>(h2, stats2, g2, be2, Wd, bd, (float*)d_out);
}

// Round 12
// 344.993 us; speedup vs baseline: 2.3835x; 1.0203x over previous
//
#include <hip/hip_runtime.h>

#define NODES   65536      // B*N
#define NGRAPH  512        // N
#define BATCH   128        // B
#define HID     128
#define TOUT    12
#define MAXDEG  10
#define NDEG    11
#define EPSV    1e-5f
#define MT      128                // nodes per conv tile
#define NTILES  (NODES / MT + NDEG)   // 523
#define PCAP    544                   // partials rows capacity (mult of 4)

typedef float f32x4 __attribute__((ext_vector_type(4)));

__device__ __forceinline__ f32x4 ntload(const float* p) {
    return __builtin_nontemporal_load((const f32x4*)p);
}
__device__ __forceinline__ void ntstore(float* p, f32x4 v) {
    __builtin_nontemporal_store(v, (f32x4*)p);
}
__device__ __forceinline__ f32x4 bnrelu4(f32x4 v, f32x4 sc, f32x4 sh) {
    f32x4 r;
    r.x = fmaxf(fmaf(v.x, sc.x, sh.x), 0.f);
    r.y = fmaxf(fmaf(v.y, sc.y, sh.y), 0.f);
    r.z = fmaxf(fmaf(v.z, sc.z, sh.z), 0.f);
    r.w = fmaxf(fmaf(v.w, sc.w, sh.w), 0.f);
    return r;
}

// ---------------------------------------------------------------- zero state
__global__ void k_zero(f32x4* part4, float* stats1, float* stats2, int* cnt) {
    int i = blockIdx.x * 256 + threadIdx.x;       // grid PCAP/4 -> PCAP*256 floats
    part4[i] = 0.f;
    if (blockIdx.x == 0) {
        stats1[threadIdx.x] = 0.f;
        stats2[threadIdx.x] = 0.f;
        if (threadIdx.x < 16) cnt[threadIdx.x] = 0;
    }
}

// ---------------------------------------------------------------- bucket nodes by degree
__global__ void k_bucket(const int* __restrict__ deg, int* __restrict__ cnt,
                         int* __restrict__ lists) {
    __shared__ int s_cnt[NDEG];
    __shared__ int s_base[NDEG];
    int t = threadIdx.x;
    if (t < NDEG) s_cnt[t] = 0;
    __syncthreads();
    int i = blockIdx.x * 256 + t;
    int d = deg[i];
    d = d < 0 ? 0 : (d > MAXDEG ? MAXDEG : d);
    int pos = atomicAdd(&s_cnt[d], 1);
    __syncthreads();
    if (t < NDEG) s_base[t] = atomicAdd(&cnt[t], s_cnt[t]);
    __syncthreads();
    lists[d * NODES + s_base[d] + pos] = i;
}

// ---------------------------------------------------------------- tile table
__global__ void k_plan(const int* __restrict__ cnt, int* __restrict__ offs) {
    if (threadIdx.x == 0) {
        int acc = 0;
        offs[0] = 0;
        for (int d = 0; d < NDEG; ++d) {
            acc += (cnt[d] + MT - 1) / MT;
            offs[d + 1] = acc;
        }
    }
}

// ---------------------------------------------------------------- build concatenated weights/biases
__global__ void k_build1(const float* __restrict__ Ws, const float* __restrict__ Wn,
                         float* __restrict__ Wcat) {
    int idx = blockIdx.x * 256 + threadIdx.x;     // grid 220
    int h4 = idx & 31;
    int k  = (idx >> 5) % 160;
    int d  = idx / (160 * 32);
    f32x4 v = 0.f;
    if (k < 75)
        v = *(const f32x4*)(Ws + ((size_t)d * 75 + k) * 128 + h4 * 4);
    else if (k >= 80 && k < 155 && d >= 1)
        v = *(const f32x4*)(Wn + ((size_t)(d - 1) * 75 + (k - 80)) * 128 + h4 * 4);
    *(f32x4*)(Wcat + ((size_t)d * 160 + k) * 128 + h4 * 4) = v;
}
__global__ void k_build2(const float* __restrict__ Ws, const float* __restrict__ Wn,
                         float* __restrict__ Wcat) {
    int idx = blockIdx.x * 256 + threadIdx.x;     // grid 352
    int h4 = idx & 31;
    int k  = (idx >> 5) & 255;
    int d  = idx >> 13;
    f32x4 v = 0.f;
    if (k < 128)
        v = *(const f32x4*)(Ws + ((size_t)d * 128 + k) * 128 + h4 * 4);
    else if (d >= 1)
        v = *(const f32x4*)(Wn + ((size_t)(d - 1) * 128 + (k - 128)) * 128 + h4 * 4);
    *(f32x4*)(Wcat + ((size_t)d * 256 + k) * 128 + h4 * 4) = v;
}
__global__ void k_bias(const float* bs1, const float* bn1, const float* bs2, const float* bn2,
                       float* bcat1, float* bcat2) {
    int d = blockIdx.x, t = threadIdx.x;          // 11 x 256
    if (t < 128) bcat1[d * 128 + t] = bs1[d * 128 + t] + (d > 0 ? bn1[(d - 1) * 128 + t] : 0.f);
    else { int h = t - 128; bcat2[d * 128 + h] = bs2[d * 128 + h] + (d > 0 ? bn2[(d - 1) * 128 + h] : 0.f); }
}

// ---------------------------------------------------------------- layer-1 pack: feats1[node][160] = [x(75)|0(5)|ns1(80)]
__global__ void k_ns1(const float* __restrict__ x, const int* __restrict__ adj,
                      const int* __restrict__ deg, float* __restrict__ feats1) {
    int idx = blockIdx.x * 256 + threadIdx.x;     // grid 5120
    int node = idx / 20;
    int q = idx - node * 20;
    int f = q * 4;
    int d = deg[node];
    d = d < 0 ? 0 : (d > MAXDEG ? MAXDEG : d);
    const int* arow = adj + node * MAXDEG;
    int base = node & ~(NGRAPH - 1);
    f32x4 s = 0.f;
    for (int k = 0; k < d; ++k) {
        const float* xr = x + (size_t)(base + arow[k]) * 75 + f;
        if (f + 3 < 75) { s.x += xr[0]; s.y += xr[1]; s.z += xr[2]; s.w += xr[3]; }
        else {
            if (f + 0 < 75) s.x += xr[0];
            if (f + 1 < 75) s.y += xr[1];
            if (f + 2 < 75) s.z += xr[2];
        }
    }
    *(f32x4*)(feats1 + (size_t)node * 160 + 80 + f) = s;
    f32x4 v = 0.f;
    const float* xs = x + (size_t)node * 75 + f;
    if (f + 3 < 75) { v.x = xs[0]; v.y = xs[1]; v.z = xs[2]; v.w = xs[3]; }
    else {
        if (f + 0 < 75) v.x = xs[0];
        if (f + 1 < 75) v.y = xs[1];
        if (f + 2 < 75) v.z = xs[2];
    }
    *(f32x4*)(feats1 + (size_t)node * 160 + f) = v;
}

// ---------------------------------------------------------------- BN1 scale/shift from stats
__global__ void k_scale(const float* __restrict__ stats, const float* __restrict__ g,
                        const float* __restrict__ be, float* __restrict__ sc,
                        float* __restrict__ sh) {
    int c = threadIdx.x;              // 128
    const float inv = 1.f / (float)NODES;
    float mu  = stats[c] * inv;
    float var = stats[HID + c] * inv - mu * mu;
    float rs  = rsqrtf(var + EPSV);
    float s   = g[c] * rs;
    sc[c] = s;
    sh[c] = be[c] - mu * s;
}

// ---------------------------------------------------------------- layer-2 gather with fused BN1+ReLU
// ns2[node][f] = sum_nbr relu(sc*h1[nbr][f]+sh); h1 stays raw.
__global__ void k_ns2(const float* __restrict__ h1, const int* __restrict__ adj,
                      const int* __restrict__ deg, const float* __restrict__ sc,
                      const float* __restrict__ sh, float* __restrict__ ns2) {
    int idx = blockIdx.x * 256 + threadIdx.x;     // grid 8192
    int node = idx >> 5;
    int f = (idx & 31) * 4;
    int d = deg[node];
    d = d < 0 ? 0 : (d > MAXDEG ? MAXDEG : d);
    const int* arow = adj + node * MAXDEG;
    int base = node & ~(NGRAPH - 1);
    f32x4 sc4 = *(const f32x4*)(sc + f);
    f32x4 sh4 = *(const f32x4*)(sh + f);
    f32x4 s = 0.f;
    for (int k = 0; k < d; ++k) {
        f32x4 v = *(const f32x4*)(h1 + (size_t)(base + arow[k]) * HID + f);
        s += bnrelu4(v, sc4, sh4);
    }
    *(f32x4*)(ns2 + (size_t)node * HID + f) = s;
}

// ---------------------------------------------------------------- conv: grouped GEMM, 8x8 register tile
// Block: 128 nodes x 128 cols, 256 thr (4 waves), each 8 rows x 8 cols.
// K chunked by 16, reg-prefetch dbuf W+F^T in LDS (~34 KB). Grid-limited ~2 blocks/CU.
// BN=true (conv2): self cols get relu(sc*v+sh) at staging; F from h1/ns2 dense.
template<int S, bool BN>
__global__ __launch_bounds__(256, 2)
void k_conv(const float* __restrict__ f160, const float* __restrict__ h1,
            const float* __restrict__ ns2, const float* __restrict__ Wcat,
            const float* __restrict__ bcat, const float* __restrict__ sc,
            const float* __restrict__ sh, const int* __restrict__ lists,
            const int* __restrict__ cnt, const int* __restrict__ offs,
            float* __restrict__ out, float* __restrict__ partials) {
    constexpr int NCH = S / 16;

    __shared__ int   s_ids[MT];
    __shared__ float sW[2][16][128];
    __shared__ float sF[2][16][132];   // transposed: sF[k][row]

    const int bid = blockIdx.x;
    if (bid >= offs[NDEG]) return;
    int d = 0;
    #pragma unroll
    for (int q = 1; q < NDEG; ++q) d += (bid >= offs[q]);
    const int c  = cnt[d];
    const int m0 = (bid - offs[d]) * MT;
    const int mv = min(MT, c - m0);
    const int t  = threadIdx.x;

    if (t < MT) s_ids[t] = lists[d * NODES + m0 + (t < mv ? t : 0)];
    __syncthreads();

    // staging roles
    const int kw = t >> 4;             // W row 0..15
    const int cw = (t & 15) * 8;       // W col base (2 f32x4)
    const int fr = t >> 1;             // F row 0..127
    const int k8 = (t & 1) * 8;        // F k base (2 f32x4)
    const float* Wbase = Wcat + (size_t)d * S * 128;
    const int fid = s_ids[fr];
    const float* Frow1 = (S == 160) ? (f160 + (size_t)fid * 160) : nullptr;
    const float* FrowS = (S == 256) ? (h1 + (size_t)fid * 128) : nullptr;
    const float* FrowN = (S == 256) ? (ns2 + (size_t)fid * 128) : nullptr;

    f32x4 w0, w1, f0, f1;
    auto LOAD = [&](int ch) {
        const float* wp = Wbase + (size_t)(ch * 16 + kw) * 128 + cw;
        w0 = *(const f32x4*)(wp);
        w1 = *(const f32x4*)(wp + 4);
        if constexpr (S == 160) {
            const float* fp = Frow1 + ch * 16 + k8;
            f0 = ntload(fp);
            f1 = ntload(fp + 4);
        } else {
            if (ch < 8) {
                const float* fp = FrowS + ch * 16 + k8;
                f0 = ntload(fp);
                f1 = ntload(fp + 4);
                if constexpr (BN) {
                    int cc = ch * 16 + k8;
                    f0 = bnrelu4(f0, *(const f32x4*)(sc + cc), *(const f32x4*)(sh + cc));
                    f1 = bnrelu4(f1, *(const f32x4*)(sc + cc + 4), *(const f32x4*)(sh + cc + 4));
                }
            } else {
                const float* fp = FrowN + (ch - 8) * 16 + k8;
                f0 = ntload(fp);
                f1 = ntload(fp + 4);
            }
        }
    };
    auto STORE = [&](int buf) {
        *(f32x4*)&sW[buf][kw][cw]     = w0;
        *(f32x4*)&sW[buf][kw][cw + 4] = w1;
        sF[buf][k8 + 0][fr] = f0.x; sF[buf][k8 + 1][fr] = f0.y;
        sF[buf][k8 + 2][fr] = f0.z; sF[buf][k8 + 3][fr] = f0.w;
        sF[buf][k8 + 4][fr] = f1.x; sF[buf][k8 + 5][fr] = f1.y;
        sF[buf][k8 + 6][fr] = f1.z; sF[buf][k8 + 7][fr] = f1.w;
    };

    const int cg = t & 15;             // col group: cols cg*8..+7
    const int rg = t >> 4;             // row group: rows rg*8..+7

    f32x4 acc[8][2];
    {
        f32x4 b0 = *(const f32x4*)(bcat + d * HID + cg * 8);
        f32x4 b1 = *(const f32x4*)(bcat + d * HID + cg * 8 + 4);
        #pragma unroll
        for (int j = 0; j < 8; ++j) { acc[j][0] = b0; acc[j][1] = b1; }
    }

    LOAD(0); STORE(0);
    __syncthreads();

    for (int ch = 0; ch < NCH; ++ch) {
        const int buf = ch & 1;
        const bool more = (ch + 1 < NCH);
        if (more) LOAD(ch + 1);        // issue early; LDS-write after compute
        #pragma unroll 4
        for (int k = 0; k < 16; ++k) {
            f32x4 wA = *(const f32x4*)&sW[buf][k][cg * 8];
            f32x4 wB = *(const f32x4*)&sW[buf][k][cg * 8 + 4];
            f32x4 fA = *(const f32x4*)&sF[buf][k][rg * 8];
            f32x4 fB = *(const f32x4*)&sF[buf][k][rg * 8 + 4];
            acc[0][0] += fA.x * wA;  acc[0][1] += fA.x * wB;
            acc[1][0] += fA.y * wA;  acc[1][1] += fA.y * wB;
            acc[2][0] += fA.z * wA;  acc[2][1] += fA.z * wB;
            acc[3][0] += fA.w * wA;  acc[3][1] += fA.w * wB;
            acc[4][0] += fB.x * wA;  acc[4][1] += fB.x * wB;
            acc[5][0] += fB.y * wA;  acc[5][1] += fB.y * wB;
            acc[6][0] += fB.z * wA;  acc[6][1] += fB.z * wB;
            acc[7][0] += fB.w * wA;  acc[7][1] += fB.w * wB;
        }
        if (more) STORE(buf ^ 1);      // safe: all waves past barrier of prev iter
        __syncthreads();
    }

    // epilogue: NT store rows (dense, OS=128) + BN partial sums (valid rows only)
    f32x4 cs0 = 0.f, cs1 = 0.f, cq0 = 0.f, cq1 = 0.f;
    #pragma unroll
    for (int j = 0; j < 8; ++j) {
        int i = rg * 8 + j;
        if (i < mv) {
            float* op = out + (size_t)s_ids[i] * HID + cg * 8;
            ntstore(op, acc[j][0]);
            ntstore(op + 4, acc[j][1]);
            cs0 += acc[j][0]; cs1 += acc[j][1];
            cq0 += acc[j][0] * acc[j][0]; cq1 += acc[j][1] * acc[j][1];
        }
    }
    __syncthreads();
    float* red = &sW[0][0][0];         // 16 rg x 256 floats = 4096 = sizeof(sW)
    *(f32x4*)&red[rg * 256 + cg * 8]           = cs0;
    *(f32x4*)&red[rg * 256 + cg * 8 + 4]       = cs1;
    *(f32x4*)&red[rg * 256 + 128 + cg * 8]     = cq0;
    *(f32x4*)&red[rg * 256 + 128 + cg * 8 + 4] = cq1;
    __syncthreads();
    {
        float tot = 0.f;
        #pragma unroll
        for (int g = 0; g < 16; ++g) tot += red[g * 256 + t];
        partials[(size_t)bid * 256 + t] = tot;   // bid unique: plain store
    }
}

// ---------------------------------------------------------------- drain BN partials (and re-zero)
__global__ void k_redstats(float* __restrict__ partials, float* __restrict__ stats) {
    int t = threadIdx.x;
    float acc = 0.f;
    for (int bx = blockIdx.x; bx < PCAP; bx += gridDim.x) {
        float* p = partials + (size_t)bx * 256 + t;
        acc += *p;
        *p = 0.f;
    }
    atomicAdd(&stats[t], acc);
}

// ---------------------------------------------------------------- BN2 + ReLU + mean over N + dense
__global__ void k_pool_dense(const float* __restrict__ h2, const float* __restrict__ stats,
                             const float* __restrict__ gamma, const float* __restrict__ beta,
                             const float* __restrict__ Wd, const float* __restrict__ bd,
                             float* __restrict__ outp) {
    __shared__ float s_part[4][HID];
    __shared__ float s_pool[HID];
    const int b = blockIdx.x;
    const int t = threadIdx.x;        // 512
    const int hcol = t & (HID - 1);
    const int q = t >> 7;             // 0..3
    const float inv = 1.f / (float)NODES;
    float mu  = stats[hcol] * inv;
    float var = stats[HID + hcol] * inv - mu * mu;
    float rs  = rsqrtf(var + EPSV);
    float sc  = gamma[hcol] * rs;
    float sh  = beta[hcol] - mu * sc;
    float acc = 0.f;
    const float* hp = h2 + ((size_t)b * NGRAPH + q * 128) * HID + hcol;
    #pragma unroll 4
    for (int n = 0; n < 128; ++n)
        acc += fmaxf(fmaf(hp[(size_t)n * HID], sc, sh), 0.f);
    s_part[q][hcol] = acc;
    __syncthreads();
    if (t < HID)
        s_pool[t] = (s_part[0][t] + s_part[1][t] + s_part[2][t] + s_part[3][t]) * (1.f / NGRAPH);
    __syncthreads();
    if (t < TOUT) {
        float o = bd[t];
        for (int hh = 0; hh < HID; ++hh)
            o = fmaf(s_pool[hh], Wd[hh * TOUT + t], o);
        outp[b * TOUT + t] = o;
    }
}

// ---------------------------------------------------------------- launch
extern "C" void kernel_launch(void* const* d_in, const int* in_sizes, int n_in,
                              void* d_out, int out_size, void* d_ws, size_t ws_size,
                              hipStream_t stream) {
    const float* x   = (const float*)d_in[0];
    const int*   adj = (const int*)d_in[1];
    const int*   deg = (const int*)d_in[2];
    const float* Wn1 = (const float*)d_in[3];
    const float* Ws1 = (const float*)d_in[4];
    const float* bn1 = (const float*)d_in[5];
    const float* bs1 = (const float*)d_in[6];
    const float* g1  = (const float*)d_in[7];
    const float* be1 = (const float*)d_in[8];
    const float* Wn2 = (const float*)d_in[9];
    const float* Ws2 = (const float*)d_in[10];
    const float* bn2 = (const float*)d_in[11];
    const float* bs2 = (const float*)d_in[12];
    const float* g2  = (const float*)d_in[13];
    const float* be2 = (const float*)d_in[14];
    const float* Wd  = (const float*)d_in[15];
    const float* bd  = (const float*)d_in[16];

    float* ws     = (float*)d_ws;
    float* feats1 = ws;                          // 10,485,760 f  [x|pad|ns1], stride 160
    float* h2     = ws;                          // alias: feats1 dead when conv2 writes
    float* h1     = ws + 10485760;               // 8,388,608 f   dense conv1 out (raw)
    float* ns2    = ws + 18874368;               // 8,388,608 f   dense, bnrelu'd-gather sum
    float* Wcat1  = ws + 27262976;               // 225,280
    float* Wcat2  = ws + 27488256;               // 360,448
    float* bcat1  = ws + 27848704;               // 1,408
    float* bcat2  = ws + 27850112;               // 1,408
    float* part   = ws + 27851520;               // 139,264 (PCAP*256)
    float* stats1 = ws + 27990784;               // 256
    float* stats2 = ws + 27991040;               // 256
    float* sc1    = ws + 27991296;               // 128
    float* sh1    = ws + 27991424;               // 128
    int*   cnt    = (int*)(ws + 27991552);       // 16
    int*   offs   = cnt + 16;                    // 16
    int*   lists  = cnt + 32;                    // 720,896 ints -> total ~114.9 MB

    k_zero<<<PCAP / 4, 256, 0, stream>>>((f32x4*)part, stats1, stats2, cnt);
    k_bucket<<<NODES / 256, 256, 0, stream>>>(deg, cnt, lists);
    k_plan<<<1, 64, 0, stream>>>(cnt, offs);
    k_build1<<<220, 256, 0, stream>>>(Ws1, Wn1, Wcat1);
    k_build2<<<352, 256, 0, stream>>>(Ws2, Wn2, Wcat2);
    k_bias<<<NDEG, 256, 0, stream>>>(bs1, bn1, bs2, bn2, bcat1, bcat2);

    // ----- layer 1: pack feats1, conv -> dense raw h1
    k_ns1<<<NODES * 20 / 256, 256, 0, stream>>>(x, adj, deg, feats1);
    k_conv<160, false><<<NTILES, 256, 0, stream>>>(feats1, nullptr, nullptr, Wcat1, bcat1,
                                                   nullptr, nullptr, lists, cnt, offs,
                                                   h1, part);
    k_redstats<<<32, 256, 0, stream>>>(part, stats1);
    k_scale<<<1, 128, 0, stream>>>(stats1, g1, be1, sc1, sh1);

    // ----- layer 2: fused-BN gather -> ns2, conv (BN on self cols) -> h2
    k_ns2<<<8192, 256, 0, stream>>>(h1, adj, deg, sc1, sh1, ns2);
    k_conv<256, true><<<NTILES, 256, 0, stream>>>(nullptr, h1, ns2, Wcat2, bcat2,
                                                  sc1, sh1, lists, cnt, offs,
                                                  h2, part);
    k_redstats<<<32, 256, 0, stream>>>(part, stats2);

    // ----- BN2 + ReLU + pool + dense
    k_pool_dense<<<BATCH, 512, 0, stream>>>(h2, stats2, g2, be2, Wd, bd, (float*)d_out);
}